// Round 4
// baseline (578.755 us; speedup 1.0000x reference)
//
#include <hip/hip_runtime.h>
#include <hip/hip_fp16.h>

// Problem constants (from reference): OUT=4096, IN=4096, G=16, TOK=8192
#define M_TOK 8192
#define N_OUT 4096
#define K_IN  4096
#define GRP   16

typedef __bf16 bf16x8 __attribute__((ext_vector_type(8)));
typedef float  f32x4  __attribute__((ext_vector_type(4)));
typedef unsigned short ushort8 __attribute__((ext_vector_type(8)));

__device__ __forceinline__ float bfbits(unsigned short h) {
    unsigned int u = ((unsigned int)h) << 16;
    return __builtin_bit_cast(float, u);
}

// async global->LDS, 16B per lane. LDS dest = wave-uniform base + lane*16 (linear).
#define GLDS16(gp, sp) __builtin_amdgcn_global_load_lds(                      \
        (const __attribute__((address_space(1))) void*)(gp),                  \
        (__attribute__((address_space(3))) void*)(sp), 16, 0, 0)

// ---------------------------------------------------------------------------
// Wave-parallel dtype detection (per block).
//   s_modes[0]: x storage    1=bf16, 0=f32   (even halfwords 0..126)
//   s_modes[1]: norm storage 0=fp16, 1=bf16, 2=f32  (halfwords 0..31)
//   s_modes[2]: bias storage 1=bf16, 0=f32   (even halfwords 0..126)
// ---------------------------------------------------------------------------
__device__ __forceinline__ void detect_block(const void* __restrict__ xv,
                                             const void* __restrict__ nrmv,
                                             const void* __restrict__ biasv,
                                             int* s_modes) {
    const int tid = threadIdx.x;
    if (tid < 64) {
        const unsigned short* px = (const unsigned short*)xv;
        unsigned short hx = px[tid * 2];
        int ex = (hx >> 7) & 0xFF;
        bool xok = ((ex >= 64 && ex <= 134) || (hx & 0x7FFF) == 0);
        unsigned long long xb = __ballot(xok);

        const unsigned short* pn = (const unsigned short*)nrmv;
        unsigned short hn = pn[tid & 31];
        float v16 = __half2float(__builtin_bit_cast(__half, hn));
        float vbf = bfbits(hn);
        unsigned long long b16 = __ballot(v16 > 0.0085f && v16 < 1.02f);  // NaN->false
        unsigned long long bbf = __ballot(vbf > 0.0085f && vbf < 1.02f);

        const unsigned short* pb = (const unsigned short*)biasv;
        unsigned short hb = pb[tid * 2];
        int eb = (hb >> 7) & 0xFF;
        bool bok = ((eb >= 64 && eb <= 134) || (hb & 0x7FFF) == 0);
        unsigned long long bb = __ballot(bok);

        if (tid == 0) {
            s_modes[0] = (xb == ~0ULL) ? 1 : 0;
            s_modes[1] = (b16 == ~0ULL) ? 0 : ((bbf == ~0ULL) ? 1 : 2);
            s_modes[2] = (bb == ~0ULL) ? 1 : 0;
        }
    }
    __syncthreads();
}

// ---------------------------------------------------------------------------
// Fused prep kernel: blocks [0,4096) dequant W -> bf16 ws; blocks [4096,6144)
// convert x f32->bf16 ws (early-exit if x already bf16).
// ---------------------------------------------------------------------------
__global__ __launch_bounds__(256) void prep_all(const void* __restrict__ xv,
                                                const int* __restrict__ q4,
                                                const void* __restrict__ nrmv,
                                                const void* __restrict__ biasv,
                                                __bf16* __restrict__ W,
                                                __bf16* __restrict__ X) {
    __shared__ int s_modes[3];
    detect_block(xv, nrmv, biasv, s_modes);
    const int tid = threadIdx.x;

    if (blockIdx.x < 4096) {
        const int nmode = s_modes[1];
        const int t = blockIdx.x * 256 + tid;              // 0 .. N*K/G-1
        const int4* qp = (const int4*)q4 + (size_t)t * 2;  // 8 int32 = 16 nibble pairs
        int4 a4 = qp[0], c4 = qp[1];
        float nm;
        if (nmode == 0)      nm = __half2float(((const __half*)nrmv)[t]);
        else if (nmode == 1) nm = bfbits(((const unsigned short*)nrmv)[t]);
        else                 nm = ((const float*)nrmv)[t];
        float s = nm * (2.0f / 15.0f);   // w = q*(2*norm/15) - norm
        int qs[8] = {a4.x, a4.y, a4.z, a4.w, c4.x, c4.y, c4.z, c4.w};
        bf16x8 v0, v1;
#pragma unroll
        for (int u = 0; u < 8; ++u) {
            float lo = fmaf((float)(qs[u] & 15), s, -nm);
            float hi = fmaf((float)((qs[u] >> 4) & 15), s, -nm);
            if (u < 4) { v0[2 * u] = (__bf16)lo; v0[2 * u + 1] = (__bf16)hi; }
            else       { v1[2 * (u - 4)] = (__bf16)lo; v1[2 * (u - 4) + 1] = (__bf16)hi; }
        }
        bf16x8* wp = (bf16x8*)(W + (size_t)t * 16);
        wp[0] = v0; wp[1] = v1;
    } else {
        if (s_modes[0] == 1) return;   // x already bf16
        const int bx = blockIdx.x - 4096;                 // 0..2047
        const int total8 = M_TOK * K_IN / 8;
        const int stride = 2048 * 256;
        for (int i = bx * 256 + tid; i < total8; i += stride) {
            const float4* fp = (const float4*)xv + (size_t)i * 2;
            float4 f0 = fp[0], f1 = fp[1];
            bf16x8 u;
            u[0] = (__bf16)f0.x; u[1] = (__bf16)f0.y; u[2] = (__bf16)f0.z; u[3] = (__bf16)f0.w;
            u[4] = (__bf16)f1.x; u[5] = (__bf16)f1.y; u[6] = (__bf16)f1.z; u[7] = (__bf16)f1.w;
            *(bf16x8*)(X + (size_t)i * 8) = u;
        }
    }
}

// ---------------------------------------------------------------------------
// GEMM: m201-template 8-phase 256x256, BK=64, 512 threads = 8 waves (2M x 4N).
// Per-wave output 128x64 = acc[8][4]; 64 MFMA / K64-tile / wave.
// LDS: A,B each [2 dbuf][2 half][128 rows][64 cols] bf16 = 64 KB -> 128 KB.
// Even K-tiles live in buf0, odd in buf1.
//
// st_16x32 swizzle (T2): byte ^= ((byte>>9)&1)<<5, i.e. 16B-block
// b' = b ^ (((row>>2)&1)<<1). Write side: LDS linear (glds requirement),
// per-thread GLOBAL source col pre-swizzled (rule 21: same involution both
// sides). Read side: qs = q ^ (((r>>2)&1)<<1), lane-constant.
//
// Phase (h,p), h = i-half, p = j-pair: 12 ds_read_b128 (af[4][2ks] +
// bfr[2][2ks]), one half-tile stage (2 glds), then
// {[vmcnt], s_barrier, lgkmcnt(0), sched_barrier(0) (rule 18),
//  setprio(1), 16 MFMA, setprio(0), s_barrier}.
//
// Region deaths within a tile's 4 phases (ph1=(0,0) ph2=(0,1) ph3=(1,0)
// ph4=(1,1)): A-low (rows 0-63 & 128-191) dead after ph2; A-high after ph4;
// B-half0/1 read every phase, dead after ph4.
// Staging assignment (tiles t=2i,t+1 computed this iter; stage issued only
// after the target region's death barrier):
//   ph1: H2(t+1)  [buf1 A-high: dead prev ph8]
//   ph2: H3(t+1)  [buf1 B0-127: dead prev ph8]
//   ph3: H4(t+1)  [buf1 B128-255: dead prev ph8]
//   ph4: H1(t+2)  [buf0 A-low: dead ph2]      + vmcnt(2)
//   ph5: H2(t+2)  [buf0 A-high: dead ph4]
//   ph6: H3(t+2)  [buf0 B0-127: dead ph4]
//   ph7: H4(t+2)  [buf0 B128-255: dead ph4]
//   ph8: H1(t+3)  [buf1 A-low: dead ph6]      + vmcnt(2)
// vmcnt ledger (per-wave, 2 ops/half): at ph4 wait, newest 2 ops = H1(t+2)
// -> H2..H4(t+1) + H1(t+1) all landed -> phases 5-8 (tile t+1) safe.
// At ph8 wait, newest 2 = H1(t+3) -> tile t+2 fully landed -> next ph1 safe.
// Counted, never 0 in steady state (T4). Prologue: stage tile 0 + H1(1),
// vmcnt(2), barrier. Last iter (i=31): ph4-8 stages skipped, ph4 drains 0.
// ---------------------------------------------------------------------------
#define PHASE(d, h, p, WT, ...) do {                                          \
    const __bf16* Ar_ = As + (d)*16384 + aregion;                             \
    const __bf16* Br_ = Bs + (d)*16384 + bregion;                             \
    bf16x8 af_[4][2], bv_[2][2];                                              \
    _Pragma("unroll")                                                         \
    for (int ii = 0; ii < 4; ++ii) {                                          \
        const int R_ = (((h)*4 + ii)*16 + r) * 64;                            \
        af_[ii][0] = *(const bf16x8*)(Ar_ + R_ + qs8);                        \
        af_[ii][1] = *(const bf16x8*)(Ar_ + R_ + 32 + qs8);                   \
    }                                                                         \
    _Pragma("unroll")                                                         \
    for (int jj = 0; jj < 2; ++jj) {                                          \
        const int RB_ = (brow0 + ((p)*2 + jj)*16 + r) * 64;                   \
        bv_[jj][0] = *(const bf16x8*)(Br_ + RB_ + qs8);                       \
        bv_[jj][1] = *(const bf16x8*)(Br_ + RB_ + 32 + qs8);                  \
    }                                                                         \
    __VA_ARGS__                                                               \
    if ((WT) == 2) asm volatile("s_waitcnt vmcnt(2)" ::: "memory");           \
    if ((WT) == 1) asm volatile("s_waitcnt vmcnt(0)" ::: "memory");           \
    __builtin_amdgcn_s_barrier();                                             \
    asm volatile("s_waitcnt lgkmcnt(0)" ::: "memory");                        \
    __builtin_amdgcn_sched_barrier(0);                                        \
    __builtin_amdgcn_s_setprio(1);                                            \
    _Pragma("unroll")                                                         \
    for (int ii = 0; ii < 4; ++ii)                                            \
    _Pragma("unroll")                                                         \
    for (int jj = 0; jj < 2; ++jj) {                                          \
        acc[(h)*4+ii][(p)*2+jj] = __builtin_amdgcn_mfma_f32_16x16x32_bf16(    \
            af_[ii][0], bv_[jj][0], acc[(h)*4+ii][(p)*2+jj], 0, 0, 0);        \
        acc[(h)*4+ii][(p)*2+jj] = __builtin_amdgcn_mfma_f32_16x16x32_bf16(    \
            af_[ii][1], bv_[jj][1], acc[(h)*4+ii][(p)*2+jj], 0, 0, 0);        \
    }                                                                         \
    __builtin_amdgcn_s_setprio(0);                                            \
    __builtin_amdgcn_s_barrier();                                             \
} while (0)

__global__ __launch_bounds__(512, 1) void gemm8ph(
        const void* __restrict__ xv, const __bf16* __restrict__ Xws,
        const __bf16* __restrict__ W, const void* __restrict__ nrmv,
        const void* __restrict__ biasv, float* __restrict__ out) {
    __shared__ __align__(16) __bf16 As[2 * 16384];   // [d][half][128][64]
    __shared__ __align__(16) __bf16 Bs[2 * 16384];
    __shared__ int s_modes[3];

    detect_block(xv, nrmv, biasv, s_modes);
    const int xmode = s_modes[0];
    const int bmode = s_modes[2];
    const __bf16* A = xmode ? (const __bf16*)xv : Xws;

    const int bid = blockIdx.x;                // no XCD swizzle (r2: L3-fit regression)
    const int n0 = (bid & 15) * 256;
    const int m0 = (bid >> 4) * 256;

    const int tid = threadIdx.x;
    const int w  = tid >> 6;          // wave 0..7
    const int l  = tid & 63;
    const int r  = l & 15;
    const int q  = l >> 4;            // 0..3
    const int wm = (w >> 2) * 128;    // waves 0-3 -> A half0, 4-7 -> half1
    const int wn = (w & 3) * 64;
    const int qs8 = (q ^ (((r >> 2) & 1) << 1)) * 8;   // st_16x32 read swizzle
    const int aregion = (w >> 2) * 8192;               // wave's A half-region
    const int bregion = ((w & 3) >> 1) * 8192;         // wave's B half-region
    const int brow0   = (w & 1) * 64;                  // row base within B region

    // staging: thread t covers 64-row glds pieces; LDS linear, global source
    // col pre-swizzled with the SAME involution: b_g = (t&7) ^ (((t>>5)&1)<<1).
    const int srow = tid >> 3;                                   // 0..63
    const int scol = ((tid & 7) ^ (((tid >> 5) & 1) << 1)) * 8;  // elems
    const __bf16* gA = A + (size_t)(m0 + srow) * K_IN + scol;
    const __bf16* gB = W + (size_t)(n0 + srow) * K_IN + scol;

    // H1/H2 = A rows {0-63,128-191}/{64-127,192-255}; H3/H4 = B rows 0-127/128-255
    auto stgA = [&](int d, int hi, int kt) {
        const size_t ko = (size_t)kt * 64;
        GLDS16(gA + (size_t)(hi * 64) * K_IN + ko,       As + d * 16384 + hi * 4096 + tid * 8);
        GLDS16(gA + (size_t)(hi * 64 + 128) * K_IN + ko, As + d * 16384 + 8192 + hi * 4096 + tid * 8);
    };
    auto stgB = [&](int d, int hi, int kt) {
        const size_t ko = (size_t)kt * 64;
        GLDS16(gB + (size_t)(hi * 128) * K_IN + ko,      Bs + d * 16384 + hi * 8192 + tid * 8);
        GLDS16(gB + (size_t)(hi * 128 + 64) * K_IN + ko, Bs + d * 16384 + hi * 8192 + 4096 + tid * 8);
    };

    // bias folded into accumulator init: C/D col = lane&15 = r
    f32x4 acc[8][4];
#pragma unroll
    for (int j = 0; j < 4; ++j) {
        const int bidx = n0 + wn + j * 16 + r;
        float bv = (bmode == 0) ? ((const float*)biasv)[bidx]
                                : bfbits(((const unsigned short*)biasv)[bidx]);
#pragma unroll
        for (int i = 0; i < 8; ++i) {
            acc[i][j][0] = bv; acc[i][j][1] = bv; acc[i][j][2] = bv; acc[i][j][3] = bv;
        }
    }

    // prologue: tile 0 fully + H1(1); wait until only H1(1)'s 2 ops in flight.
    stgA(0, 0, 0); stgA(0, 1, 0); stgB(0, 0, 0); stgB(0, 1, 0);
    stgA(1, 0, 1);
    asm volatile("s_waitcnt vmcnt(2)" ::: "memory");
    __builtin_amdgcn_s_barrier();

    for (int i = 0; i < 32; ++i) {       // 32 iters x 2 K64-tiles = K 4096
        const int k1 = 2 * i + 1, k2 = 2 * i + 2, k3 = 2 * i + 3;
        const bool st = (i < 31);
        const int wt4 = st ? 2 : 1;      // last iter: drain (no H1(t+2) issued)
        const int wt8 = st ? 2 : 0;

        PHASE(0, 0, 0, 0, stgA(1, 1, k1); );
        PHASE(0, 0, 1, 0, stgB(1, 0, k1); );
        PHASE(0, 1, 0, 0, stgB(1, 1, k1); );
        PHASE(0, 1, 1, wt4, if (st) stgA(0, 0, k2); );
        PHASE(1, 0, 0, 0, if (st) stgA(0, 1, k2); );
        PHASE(1, 0, 1, 0, if (st) stgB(0, 0, k2); );
        PHASE(1, 1, 0, 0, if (st) stgB(0, 1, k2); );
        PHASE(1, 1, 1, wt8, if (st) stgA(1, 0, k3); );
    }

    // epilogue: C/D map col=lane&15, row=(lane>>4)*4+reg  (m89-verified)
#pragma unroll
    for (int i = 0; i < 8; ++i) {
        const int row = m0 + wm + i * 16 + q * 4;
#pragma unroll
        for (int j = 0; j < 4; ++j) {
            const int col = n0 + wn + j * 16 + r;
            float* p = out + (size_t)row * N_OUT + col;
            p[0 * N_OUT] = acc[i][j][0];
            p[1 * N_OUT] = acc[i][j][1];
            p[2 * N_OUT] = acc[i][j][2];
            p[3 * N_OUT] = acc[i][j][3];
        }
    }
}

// ---------------------------------------------------------------------------
// Fallback: the round-0 verified fused kernel (used only if ws too small).
// ---------------------------------------------------------------------------
__global__ __launch_bounds__(256, 2) void gemm_fused(
        const void* __restrict__ xv,
        const int* __restrict__ q4, const void* __restrict__ nrmv,
        const void* __restrict__ biasv, float* __restrict__ out) {
    __shared__ __align__(16) __bf16 As[128 * 32];
    __shared__ __align__(16) __bf16 Bs[128 * 32];
    __shared__ int s_modes[3];

    detect_block(xv, nrmv, biasv, s_modes);
    const int tid = threadIdx.x;
    const int xmode = s_modes[0];
    const int nmode = s_modes[1];
    const int bmode = s_modes[2];

    const int bid = blockIdx.x;
    const int n0 = (bid & 31) * 128;
    const int m0 = (bid >> 5) * 128;

    const int w  = tid >> 6;
    const int l  = tid & 63;
    const int r  = l & 15;
    const int q  = l >> 4;
    const int wm = (w >> 1) * 64;
    const int wn = (w & 1) * 64;

    const int arow = tid >> 1;
    const int acol = (tid & 1) * 16;
    const size_t aoff = (size_t)(m0 + arow) * K_IN + acol;

    const int brow = tid >> 1;
    const int bgc  = tid & 1;

    f32x4 acc[4][4];
#pragma unroll
    for (int j = 0; j < 4; ++j) {
        const int bidx = n0 + wn + j * 16 + r;
        float bv = (bmode == 0) ? ((const float*)biasv)[bidx]
                                : bfbits(((const unsigned short*)biasv)[bidx]);
#pragma unroll
        for (int i = 0; i < 4; ++i) {
            acc[i][j][0] = bv; acc[i][j][1] = bv; acc[i][j][2] = bv; acc[i][j][3] = bv;
        }
    }

    for (int k0 = 0; k0 < K_IN; k0 += 32) {
        __syncthreads();
        {
            const int g = (n0 + brow) * (K_IN / GRP) + (k0 >> 4) + bgc;
            const int4* qp = (const int4*)q4 + (size_t)g * 2;
            int4 a4 = qp[0], c4 = qp[1];
            float nm;
            if (nmode == 0)      nm = __half2float(((const __half*)nrmv)[g]);
            else if (nmode == 1) nm = bfbits(((const unsigned short*)nrmv)[g]);
            else                 nm = ((const float*)nrmv)[g];
            float s = nm * (2.0f / 15.0f);
            int qs[8] = {a4.x, a4.y, a4.z, a4.w, c4.x, c4.y, c4.z, c4.w};
            bf16x8 v0, v1;
#pragma unroll
            for (int u = 0; u < 8; ++u) {
                float lo = fmaf((float)(qs[u] & 15), s, -nm);
                float hi = fmaf((float)((qs[u] >> 4) & 15), s, -nm);
                if (u < 4) { v0[2 * u] = (__bf16)lo; v0[2 * u + 1] = (__bf16)hi; }
                else       { v1[2 * (u - 4)] = (__bf16)lo; v1[2 * (u - 4) + 1] = (__bf16)hi; }
            }
            bf16x8* bp = (bf16x8*)(Bs + brow * 32 + bgc * 16);
            bp[0] = v0; bp[1] = v1;
        }

        if (xmode == 0) {
            const float4* ap = (const float4*)((const float*)xv + aoff + k0);
            float4 f0 = ap[0], f1 = ap[1], f2 = ap[2], f3 = ap[3];
            bf16x8 u0, u1;
            u0[0] = (__bf16)f0.x; u0[1] = (__bf16)f0.y; u0[2] = (__bf16)f0.z; u0[3] = (__bf16)f0.w;
            u0[4] = (__bf16)f1.x; u0[5] = (__bf16)f1.y; u0[6] = (__bf16)f1.z; u0[7] = (__bf16)f1.w;
            u1[0] = (__bf16)f2.x; u1[1] = (__bf16)f2.y; u1[2] = (__bf16)f2.z; u1[3] = (__bf16)f2.w;
            u1[4] = (__bf16)f3.x; u1[5] = (__bf16)f3.y; u1[6] = (__bf16)f3.z; u1[7] = (__bf16)f3.w;
            bf16x8* asp = (bf16x8*)(As + arow * 32 + acol);
            asp[0] = u0; asp[1] = u1;
        } else {
            const ushort8* ap = (const ushort8*)((const unsigned short*)xv + aoff + k0);
            ushort8 u0 = ap[0], u1 = ap[1];
            bf16x8* asp = (bf16x8*)(As + arow * 32 + acol);
            asp[0] = __builtin_bit_cast(bf16x8, u0);
            asp[1] = __builtin_bit_cast(bf16x8, u1);
        }

        __syncthreads();

        bf16x8 af[4], bf[4];
#pragma unroll
        for (int i = 0; i < 4; ++i)
            af[i] = *(const bf16x8*)(As + (wm + i * 16 + r) * 32 + q * 8);
#pragma unroll
        for (int j = 0; j < 4; ++j)
            bf[j] = *(const bf16x8*)(Bs + (wn + j * 16 + r) * 32 + q * 8);

#pragma unroll
        for (int i = 0; i < 4; ++i)
#pragma unroll
            for (int j = 0; j < 4; ++j)
                acc[i][j] = __builtin_amdgcn_mfma_f32_16x16x32_bf16(
                    af[i], bf[j], acc[i][j], 0, 0, 0);
    }

#pragma unroll
    for (int i = 0; i < 4; ++i) {
        const int row = m0 + wm + i * 16 + q * 4;
#pragma unroll
        for (int j = 0; j < 4; ++j) {
            const int col = n0 + wn + j * 16 + r;
            float* p = out + (size_t)row * N_OUT + col;
            p[0 * N_OUT] = acc[i][j][0];
            p[1 * N_OUT] = acc[i][j][1];
            p[2 * N_OUT] = acc[i][j][2];
            p[3 * N_OUT] = acc[i][j][3];
        }
    }
}

extern "C" void kernel_launch(void* const* d_in, const int* in_sizes, int n_in,
                              void* d_out, int out_size, void* d_ws, size_t ws_size,
                              hipStream_t stream) {
    const void* x    = d_in[0];
    const int*  q4   = (const int*)d_in[1];
    const void* nrm  = d_in[2];
    const void* bias = d_in[3];
    float*      out  = (float*)d_out;

    // workspace layout: [W bf16: N*K*2][X bf16: M*K*2]
    const size_t X_OFF = (size_t)N_OUT * K_IN * 2;
    const size_t NEED  = X_OFF + (size_t)M_TOK * K_IN * 2;   // ~100.7 MB

    if (ws_size >= NEED) {
        __bf16* W = (__bf16*)d_ws;
        __bf16* X = (__bf16*)((char*)d_ws + X_OFF);

        prep_all<<<4096 + 2048, 256, 0, stream>>>(x, q4, nrm, bias, W, X);
        gemm8ph<<<(M_TOK / 256) * (N_OUT / 256), 512, 0, stream>>>(
            x, X, W, nrm, bias, out);
    } else {
        gemm_fused<<<(M_TOK / 128) * (N_OUT / 128), 256, 0, stream>>>(
            x, q4, nrm, bias, out);
    }
}

// Round 5
// 520.262 us; speedup vs baseline: 1.1124x; 1.1124x over previous
//
#include <hip/hip_runtime.h>
#include <hip/hip_fp16.h>

// Problem constants (from reference): OUT=4096, IN=4096, G=16, TOK=8192
#define M_TOK 8192
#define N_OUT 4096
#define K_IN  4096
#define GRP   16

typedef __bf16 bf16x8 __attribute__((ext_vector_type(8)));
typedef float  f32x4  __attribute__((ext_vector_type(4)));
typedef unsigned short ushort8 __attribute__((ext_vector_type(8)));

__device__ __forceinline__ float bfbits(unsigned short h) {
    unsigned int u = ((unsigned int)h) << 16;
    return __builtin_bit_cast(float, u);
}

// async global->LDS, 16B per lane. LDS dest = wave-uniform base + lane*16 (linear).
#define GLDS16(gp, sp) __builtin_amdgcn_global_load_lds(                      \
        (const __attribute__((address_space(1))) void*)(gp),                  \
        (__attribute__((address_space(3))) void*)(sp), 16, 0, 0)

// ---------------------------------------------------------------------------
// Wave-parallel dtype detection (per block).
//   s_modes[0]: x storage    1=bf16, 0=f32   (even halfwords 0..126)
//   s_modes[1]: norm storage 0=fp16, 1=bf16, 2=f32  (halfwords 0..31)
//   s_modes[2]: bias storage 1=bf16, 0=f32   (even halfwords 0..126)
// ---------------------------------------------------------------------------
__device__ __forceinline__ void detect_block(const void* __restrict__ xv,
                                             const void* __restrict__ nrmv,
                                             const void* __restrict__ biasv,
                                             int* s_modes) {
    const int tid = threadIdx.x;
    if (tid < 64) {
        const unsigned short* px = (const unsigned short*)xv;
        unsigned short hx = px[tid * 2];
        int ex = (hx >> 7) & 0xFF;
        bool xok = ((ex >= 64 && ex <= 134) || (hx & 0x7FFF) == 0);
        unsigned long long xb = __ballot(xok);

        const unsigned short* pn = (const unsigned short*)nrmv;
        unsigned short hn = pn[tid & 31];
        float v16 = __half2float(__builtin_bit_cast(__half, hn));
        float vbf = bfbits(hn);
        unsigned long long b16 = __ballot(v16 > 0.0085f && v16 < 1.02f);  // NaN->false
        unsigned long long bbf = __ballot(vbf > 0.0085f && vbf < 1.02f);

        const unsigned short* pb = (const unsigned short*)biasv;
        unsigned short hb = pb[tid * 2];
        int eb = (hb >> 7) & 0xFF;
        bool bok = ((eb >= 64 && eb <= 134) || (hb & 0x7FFF) == 0);
        unsigned long long bb = __ballot(bok);

        if (tid == 0) {
            s_modes[0] = (xb == ~0ULL) ? 1 : 0;
            s_modes[1] = (b16 == ~0ULL) ? 0 : ((bbf == ~0ULL) ? 1 : 2);
            s_modes[2] = (bb == ~0ULL) ? 1 : 0;
        }
    }
    __syncthreads();
}

// ---------------------------------------------------------------------------
// Fused prep kernel: blocks [0,4096) dequant W -> bf16 ws; blocks [4096,6144)
// convert x f32->bf16 ws (early-exit if x already bf16).
// ---------------------------------------------------------------------------
__global__ __launch_bounds__(256) void prep_all(const void* __restrict__ xv,
                                                const int* __restrict__ q4,
                                                const void* __restrict__ nrmv,
                                                const void* __restrict__ biasv,
                                                __bf16* __restrict__ W,
                                                __bf16* __restrict__ X) {
    __shared__ int s_modes[3];
    detect_block(xv, nrmv, biasv, s_modes);
    const int tid = threadIdx.x;

    if (blockIdx.x < 4096) {
        const int nmode = s_modes[1];
        const int t = blockIdx.x * 256 + tid;              // 0 .. N*K/G-1
        const int4* qp = (const int4*)q4 + (size_t)t * 2;  // 8 int32 = 16 nibble pairs
        int4 a4 = qp[0], c4 = qp[1];
        float nm;
        if (nmode == 0)      nm = __half2float(((const __half*)nrmv)[t]);
        else if (nmode == 1) nm = bfbits(((const unsigned short*)nrmv)[t]);
        else                 nm = ((const float*)nrmv)[t];
        float s = nm * (2.0f / 15.0f);   // w = q*(2*norm/15) - norm
        int qs[8] = {a4.x, a4.y, a4.z, a4.w, c4.x, c4.y, c4.z, c4.w};
        bf16x8 v0, v1;
#pragma unroll
        for (int u = 0; u < 8; ++u) {
            float lo = fmaf((float)(qs[u] & 15), s, -nm);
            float hi = fmaf((float)((qs[u] >> 4) & 15), s, -nm);
            if (u < 4) { v0[2 * u] = (__bf16)lo; v0[2 * u + 1] = (__bf16)hi; }
            else       { v1[2 * (u - 4)] = (__bf16)lo; v1[2 * (u - 4) + 1] = (__bf16)hi; }
        }
        bf16x8* wp = (bf16x8*)(W + (size_t)t * 16);
        wp[0] = v0; wp[1] = v1;
    } else {
        if (s_modes[0] == 1) return;   // x already bf16
        const int bx = blockIdx.x - 4096;                 // 0..2047
        const int total8 = M_TOK * K_IN / 8;
        const int stride = 2048 * 256;
        for (int i = bx * 256 + tid; i < total8; i += stride) {
            const float4* fp = (const float4*)xv + (size_t)i * 2;
            float4 f0 = fp[0], f1 = fp[1];
            bf16x8 u;
            u[0] = (__bf16)f0.x; u[1] = (__bf16)f0.y; u[2] = (__bf16)f0.z; u[3] = (__bf16)f0.w;
            u[4] = (__bf16)f1.x; u[5] = (__bf16)f1.y; u[6] = (__bf16)f1.z; u[7] = (__bf16)f1.w;
            *(bf16x8*)(X + (size_t)i * 8) = u;
        }
    }
}

// ---------------------------------------------------------------------------
// GEMM: 8-phase 256x256, BK=64, 512 threads = 8 waves (2M x 4N).
// Round-5 changes vs round 4 (same barrier/phase skeleton, verified passing):
//  (a) FRAGMENT REUSE — minimal 24 ds_read_b128 per wave per K64-tile:
//      P1: A-h0 (8) + B-p0 (4); P2: B-p1 (4); P3: A-h1 (8, overwrites A-h0);
//      P4: none (register-only MFMA). B frags bva/bvb live across phases.
//      (r4 read 48/tile; counters showed LDS-read-BW bound at MfmaUtil 32%.)
//  (b) 3-bit bank swizzle: row stride is 128B == 0 mod 32 banks, so banks
//      depend on column only; stored 16B-block = logical_block ^ (row&7)
//      spreads 64 lanes uniformly over all 8 blocks = all 32 banks.
//      Write side: LDS linear (glds), GLOBAL source col pre-swizzled with
//      the same involution (rule 21): thread t fetches logical block
//      (t&7)^((t>>3)&7); every LDS row written by t has row&7 == (t>>3)&7.
//      Read side: lane needs logical block q (k 0-31) and q+4 (k 32-63):
//      stored at qs8a=(q^(r&7))*8 and qs8a^32 (row&7 == r&7 for all frags).
//
// Stage slots (one 2-glds stage per phase; tiles t=2i buf0, t+1 buf1):
//   P1: H2(t+1)->buf1  [buf1 A-high dead after prev P7]
//   P2: H1(t+2)->buf0  [buf0 A-low dead after P1]
//   P3: H3(t+2)->buf0  [buf0 B-low dead after P2]
//   P4: H4(t+2)->buf0  [buf0 B-high dead after P2]      + vmcnt(6)
//   P5: H2(t+2)->buf0  [buf0 A-high dead after P3]
//   P6: H1(t+3)->buf1  [buf1 A-low dead after P5]
//   P7: H3(t+3)->buf1  [buf1 B-low dead after P6]
//   P8: H4(t+3)->buf1  [buf1 B-high dead after P6]      + vmcnt(6)
// vmcnt ledger (2 vm-ops per stage, per wave):
//   W1@P4 vmcnt(6): newest 6 = P2,P3,P4 stages => H2(t+1) + all of tile t+1
//   landed => P5..P8 reads safe.  W2@P8 vmcnt(6): newest 6 = P6,P7,P8 =>
//   H1,H3,H4(t+2) and H2(t+2) landed => next P1 (H1,B) and P3 (H2) safe.
//   Counted, never 0 in steady state. Last iter (i=31): no stages except
//   P1's H2(63); W1 drains vmcnt(0) (covers tile-63 reads), W2 vmcnt(0).
// Prologue: stage tile0 fully + H1,H3,H4(1); vmcnt(6) leaves exactly those
// 3 stages in flight = steady-state invariant at P1 entry.
// ---------------------------------------------------------------------------
#define READ_A(d, h) do {                                                     \
    _Pragma("unroll")                                                         \
    for (int ii = 0; ii < 4; ++ii) {                                          \
        const __bf16* b_ = As + (d)*16384 + aregion                           \
                         + ((((h)*4 + ii)*16 + r) * 64);                      \
        af[ii][0] = *(const bf16x8*)(b_ + qs8a);                              \
        af[ii][1] = *(const bf16x8*)(b_ + (qs8a ^ 32));                       \
    } } while (0)

#define READ_B(d, p, BV) do {                                                 \
    _Pragma("unroll")                                                         \
    for (int jj = 0; jj < 2; ++jj) {                                          \
        const __bf16* b_ = Bs + (d)*16384 + bregion                           \
                         + ((brow0 + ((p)*2 + jj)*16 + r) * 64);              \
        BV[jj][0] = *(const bf16x8*)(b_ + qs8a);                              \
        BV[jj][1] = *(const bf16x8*)(b_ + (qs8a ^ 32));                       \
    } } while (0)

#define SYNC_MFMA(WT, h, p, BV) do {                                          \
    if ((WT) == 6) asm volatile("s_waitcnt vmcnt(6)" ::: "memory");           \
    if ((WT) == 0) asm volatile("s_waitcnt vmcnt(0)" ::: "memory");           \
    __builtin_amdgcn_s_barrier();                                             \
    asm volatile("s_waitcnt lgkmcnt(0)" ::: "memory");                        \
    __builtin_amdgcn_sched_barrier(0);                                        \
    __builtin_amdgcn_s_setprio(1);                                            \
    _Pragma("unroll")                                                         \
    for (int ii = 0; ii < 4; ++ii)                                            \
    _Pragma("unroll")                                                         \
    for (int jj = 0; jj < 2; ++jj) {                                          \
        acc[(h)*4+ii][(p)*2+jj] = __builtin_amdgcn_mfma_f32_16x16x32_bf16(    \
            af[ii][0], BV[jj][0], acc[(h)*4+ii][(p)*2+jj], 0, 0, 0);          \
        acc[(h)*4+ii][(p)*2+jj] = __builtin_amdgcn_mfma_f32_16x16x32_bf16(    \
            af[ii][1], BV[jj][1], acc[(h)*4+ii][(p)*2+jj], 0, 0, 0);          \
    }                                                                         \
    __builtin_amdgcn_s_setprio(0);                                            \
    __builtin_amdgcn_s_barrier();                                             \
} while (0)

__global__ __launch_bounds__(512, 1) void gemm8ph(
        const void* __restrict__ xv, const __bf16* __restrict__ Xws,
        const __bf16* __restrict__ W, const void* __restrict__ nrmv,
        const void* __restrict__ biasv, float* __restrict__ out) {
    __shared__ __align__(16) __bf16 As[2 * 16384];   // [d][2 half][128][64]
    __shared__ __align__(16) __bf16 Bs[2 * 16384];
    __shared__ int s_modes[3];

    detect_block(xv, nrmv, biasv, s_modes);
    const int xmode = s_modes[0];
    const int bmode = s_modes[2];
    const __bf16* A = xmode ? (const __bf16*)xv : Xws;

    const int bid = blockIdx.x;                // no XCD swizzle (r2: L3-fit regression)
    const int n0 = (bid & 15) * 256;
    const int m0 = (bid >> 4) * 256;

    const int tid = threadIdx.x;
    const int w  = tid >> 6;          // wave 0..7
    const int l  = tid & 63;
    const int r  = l & 15;
    const int q  = l >> 4;            // 0..3
    const int wm = (w >> 2) * 128;    // waves 0-3 -> A half0, 4-7 -> half1
    const int wn = (w & 3) * 64;
    const int qs8a = (q ^ (r & 7)) * 8;                // 3-bit swizzled block (elems)
    const int aregion = (w >> 2) * 8192;               // wave's A half-region
    const int bregion = ((w & 3) >> 1) * 8192;         // wave's B half-region
    const int brow0   = (w & 1) * 64;                  // row base within B region

    // staging: thread t -> stored block t&7 at LDS rows with row&7 == (t>>3)&7;
    // pre-swizzle the GLOBAL source column with the same involution.
    const int srow = tid >> 3;                                   // 0..63
    const int scol = ((tid & 7) ^ ((tid >> 3) & 7)) * 8;         // elems
    const __bf16* gA = A + (size_t)(m0 + srow) * K_IN + scol;
    const __bf16* gB = W + (size_t)(n0 + srow) * K_IN + scol;

    // H1/H2 = A rows {0-63,128-191}/{64-127,192-255}; H3/H4 = B rows 0-127/128-255
    auto stgA = [&](int d, int hi, int kt) {
        const size_t ko = (size_t)kt * 64;
        GLDS16(gA + (size_t)(hi * 64) * K_IN + ko,       As + d * 16384 + hi * 4096 + tid * 8);
        GLDS16(gA + (size_t)(hi * 64 + 128) * K_IN + ko, As + d * 16384 + 8192 + hi * 4096 + tid * 8);
    };
    auto stgB = [&](int d, int hi, int kt) {
        const size_t ko = (size_t)kt * 64;
        GLDS16(gB + (size_t)(hi * 128) * K_IN + ko,      Bs + d * 16384 + hi * 8192 + tid * 8);
        GLDS16(gB + (size_t)(hi * 128 + 64) * K_IN + ko, Bs + d * 16384 + hi * 8192 + 4096 + tid * 8);
    };

    // bias folded into accumulator init: C/D col = lane&15 = r
    f32x4 acc[8][4];
#pragma unroll
    for (int j = 0; j < 4; ++j) {
        const int bidx = n0 + wn + j * 16 + r;
        float bv = (bmode == 0) ? ((const float*)biasv)[bidx]
                                : bfbits(((const unsigned short*)biasv)[bidx]);
#pragma unroll
        for (int i = 0; i < 8; ++i) {
            acc[i][j][0] = bv; acc[i][j][1] = bv; acc[i][j][2] = bv; acc[i][j][3] = bv;
        }
    }

    bf16x8 af[4][2], bva[2][2], bvb[2][2];

    // prologue: tile 0 fully (H1,H3,H4,H2) + tile 1 (H1,H3,H4); vmcnt(6)
    // drains tile 0, leaves exactly tile 1's 3 stages in flight.
    stgA(0, 0, 0); stgB(0, 0, 0); stgB(0, 1, 0); stgA(0, 1, 0);
    stgA(1, 0, 1); stgB(1, 0, 1); stgB(1, 1, 1);
    asm volatile("s_waitcnt vmcnt(6)" ::: "memory");
    __builtin_amdgcn_s_barrier();

    for (int i = 0; i < 32; ++i) {       // 32 iters x 2 K64-tiles = K 4096
        const int k1 = 2 * i + 1, k2 = 2 * i + 2, k3 = 2 * i + 3;
        const bool st = (i < 31);
        const int wt = st ? 6 : 0;

        // ---- tile t = 2i (buf0) ----
        READ_A(0, 0); READ_B(0, 0, bva);
        stgA(1, 1, k1);                       // P1: H2(t+1)
        SYNC_MFMA(-1, 0, 0, bva);

        READ_B(0, 1, bvb);
        if (st) stgA(0, 0, k2);               // P2: H1(t+2)
        SYNC_MFMA(-1, 0, 1, bvb);

        READ_A(0, 1);
        if (st) stgB(0, 0, k2);               // P3: H3(t+2)
        SYNC_MFMA(-1, 1, 0, bva);

        if (st) stgB(0, 1, k2);               // P4: H4(t+2)
        SYNC_MFMA(wt, 1, 1, bvb);             // W1

        // ---- tile t+1 (buf1) ----
        READ_A(1, 0); READ_B(1, 0, bva);
        if (st) stgA(0, 1, k2);               // P5: H2(t+2)
        SYNC_MFMA(-1, 0, 0, bva);

        READ_B(1, 1, bvb);
        if (st) stgA(1, 0, k3);               // P6: H1(t+3)
        SYNC_MFMA(-1, 0, 1, bvb);

        READ_A(1, 1);
        if (st) stgB(1, 0, k3);               // P7: H3(t+3)
        SYNC_MFMA(-1, 1, 0, bva);

        if (st) stgB(1, 1, k3);               // P8: H4(t+3)
        SYNC_MFMA(wt, 1, 1, bvb);             // W2
    }

    // epilogue: C/D map col=lane&15, row=(lane>>4)*4+reg  (m89-verified)
#pragma unroll
    for (int i = 0; i < 8; ++i) {
        const int row = m0 + wm + i * 16 + q * 4;
#pragma unroll
        for (int j = 0; j < 4; ++j) {
            const int col = n0 + wn + j * 16 + r;
            float* p = out + (size_t)row * N_OUT + col;
            p[0 * N_OUT] = acc[i][j][0];
            p[1 * N_OUT] = acc[i][j][1];
            p[2 * N_OUT] = acc[i][j][2];
            p[3 * N_OUT] = acc[i][j][3];
        }
    }
}

// ---------------------------------------------------------------------------
// Fallback: the round-0 verified fused kernel (used only if ws too small).
// ---------------------------------------------------------------------------
__global__ __launch_bounds__(256, 2) void gemm_fused(
        const void* __restrict__ xv,
        const int* __restrict__ q4, const void* __restrict__ nrmv,
        const void* __restrict__ biasv, float* __restrict__ out) {
    __shared__ __align__(16) __bf16 As[128 * 32];
    __shared__ __align__(16) __bf16 Bs[128 * 32];
    __shared__ int s_modes[3];

    detect_block(xv, nrmv, biasv, s_modes);
    const int tid = threadIdx.x;
    const int xmode = s_modes[0];
    const int nmode = s_modes[1];
    const int bmode = s_modes[2];

    const int bid = blockIdx.x;
    const int n0 = (bid & 31) * 128;
    const int m0 = (bid >> 5) * 128;

    const int w  = tid >> 6;
    const int l  = tid & 63;
    const int r  = l & 15;
    const int q  = l >> 4;
    const int wm = (w >> 1) * 64;
    const int wn = (w & 1) * 64;

    const int arow = tid >> 1;
    const int acol = (tid & 1) * 16;
    const size_t aoff = (size_t)(m0 + arow) * K_IN + acol;

    const int brow = tid >> 1;
    const int bgc  = tid & 1;

    f32x4 acc[4][4];
#pragma unroll
    for (int j = 0; j < 4; ++j) {
        const int bidx = n0 + wn + j * 16 + r;
        float bv = (bmode == 0) ? ((const float*)biasv)[bidx]
                                : bfbits(((const unsigned short*)biasv)[bidx]);
#pragma unroll
        for (int i = 0; i < 4; ++i) {
            acc[i][j][0] = bv; acc[i][j][1] = bv; acc[i][j][2] = bv; acc[i][j][3] = bv;
        }
    }

    for (int k0 = 0; k0 < K_IN; k0 += 32) {
        __syncthreads();
        {
            const int g = (n0 + brow) * (K_IN / GRP) + (k0 >> 4) + bgc;
            const int4* qp = (const int4*)q4 + (size_t)g * 2;
            int4 a4 = qp[0], c4 = qp[1];
            float nm;
            if (nmode == 0)      nm = __half2float(((const __half*)nrmv)[g]);
            else if (nmode == 1) nm = bfbits(((const unsigned short*)nrmv)[g]);
            else                 nm = ((const float*)nrmv)[g];
            float s = nm * (2.0f / 15.0f);
            int qs[8] = {a4.x, a4.y, a4.z, a4.w, c4.x, c4.y, c4.z, c4.w};
            bf16x8 v0, v1;
#pragma unroll
            for (int u = 0; u < 8; ++u) {
                float lo = fmaf((float)(qs[u] & 15), s, -nm);
                float hi = fmaf((float)((qs[u] >> 4) & 15), s, -nm);
                if (u < 4) { v0[2 * u] = (__bf16)lo; v0[2 * u + 1] = (__bf16)hi; }
                else       { v1[2 * (u - 4)] = (__bf16)lo; v1[2 * (u - 4) + 1] = (__bf16)hi; }
            }
            bf16x8* bp = (bf16x8*)(Bs + brow * 32 + bgc * 16);
            bp[0] = v0; bp[1] = v1;
        }

        if (xmode == 0) {
            const float4* ap = (const float4*)((const float*)xv + aoff + k0);
            float4 f0 = ap[0], f1 = ap[1], f2 = ap[2], f3 = ap[3];
            bf16x8 u0, u1;
            u0[0] = (__bf16)f0.x; u0[1] = (__bf16)f0.y; u0[2] = (__bf16)f0.z; u0[3] = (__bf16)f0.w;
            u0[4] = (__bf16)f1.x; u0[5] = (__bf16)f1.y; u0[6] = (__bf16)f1.z; u0[7] = (__bf16)f1.w;
            u1[0] = (__bf16)f2.x; u1[1] = (__bf16)f2.y; u1[2] = (__bf16)f2.z; u1[3] = (__bf16)f2.w;
            u1[4] = (__bf16)f3.x; u1[5] = (__bf16)f3.y; u1[6] = (__bf16)f3.z; u1[7] = (__bf16)f3.w;
            bf16x8* asp = (bf16x8*)(As + arow * 32 + acol);
            asp[0] = u0; asp[1] = u1;
        } else {
            const ushort8* ap = (const ushort8*)((const unsigned short*)xv + aoff + k0);
            ushort8 u0 = ap[0], u1 = ap[1];
            bf16x8* asp = (bf16x8*)(As + arow * 32 + acol);
            asp[0] = __builtin_bit_cast(bf16x8, u0);
            asp[1] = __builtin_bit_cast(bf16x8, u1);
        }

        __syncthreads();

        bf16x8 af[4], bf[4];
#pragma unroll
        for (int i = 0; i < 4; ++i)
            af[i] = *(const bf16x8*)(As + (wm + i * 16 + r) * 32 + q * 8);
#pragma unroll
        for (int j = 0; j < 4; ++j)
            bf[j] = *(const bf16x8*)(Bs + (wn + j * 16 + r) * 32 + q * 8);

#pragma unroll
        for (int i = 0; i < 4; ++i)
#pragma unroll
            for (int j = 0; j < 4; ++j)
                acc[i][j] = __builtin_amdgcn_mfma_f32_16x16x32_bf16(
                    af[i], bf[j], acc[i][j], 0, 0, 0);
    }

#pragma unroll
    for (int i = 0; i < 4; ++i) {
        const int row = m0 + wm + i * 16 + q * 4;
#pragma unroll
        for (int j = 0; j < 4; ++j) {
            const int col = n0 + wn + j * 16 + r;
            float* p = out + (size_t)row * N_OUT + col;
            p[0 * N_OUT] = acc[i][j][0];
            p[1 * N_OUT] = acc[i][j][1];
            p[2 * N_OUT] = acc[i][j][2];
            p[3 * N_OUT] = acc[i][j][3];
        }
    }
}

extern "C" void kernel_launch(void* const* d_in, const int* in_sizes, int n_in,
                              void* d_out, int out_size, void* d_ws, size_t ws_size,
                              hipStream_t stream) {
    const void* x    = d_in[0];
    const int*  q4   = (const int*)d_in[1];
    const void* nrm  = d_in[2];
    const void* bias = d_in[3];
    float*      out  = (float*)d_out;

    // workspace layout: [W bf16: N*K*2][X bf16: M*K*2]
    const size_t X_OFF = (size_t)N_OUT * K_IN * 2;
    const size_t NEED  = X_OFF + (size_t)M_TOK * K_IN * 2;   // ~100.7 MB

    if (ws_size >= NEED) {
        __bf16* W = (__bf16*)d_ws;
        __bf16* X = (__bf16*)((char*)d_ws + X_OFF);

        prep_all<<<4096 + 2048, 256, 0, stream>>>(x, q4, nrm, bias, W, X);
        gemm8ph<<<(M_TOK / 256) * (N_OUT / 256), 512, 0, stream>>>(
            x, X, W, nrm, bias, out);
    } else {
        gemm_fused<<<(M_TOK / 128) * (N_OUT / 128), 256, 0, stream>>>(
            x, q4, nrm, bias, out);
    }
}